// Round 1
// baseline (400.621 us; speedup 1.0000x reference)
//
#include <hip/hip_runtime.h>
#include <math.h>

// Problem constants (fixed by reference)
#define BB   4     // batch
#define CIN  64    // C  (in channels)
#define CMID 32    // CI (inter channels)
#define HS   96
#define WS   96
#define H2   48
#define W2   48
#define H4   24
#define W4   24
#define N2   (H2*W2)   // 2304 distinct queries
#define M4   (H4*W4)   // 576 distinct keys

// ---------------------------------------------------------------------------
// K1: 3x3 stride-2 pad-1 convs: cz=0 theta(x) -> T[4][32][48][48]
//     cz=1 phi(x), cz=2 phi_pan(x_pan) -> maxpool2 -> Kp[2][4][32][24][24]
// Block: (p row-pair 0..23, b, cz). 256 threads: co = tid&31, g = tid>>5,
// each thread computes 2 rows x 6 contiguous cols for its co.
// ---------------------------------------------------------------------------
__global__ __launch_bounds__(256) void conv3x3_kernel(
    const float* __restrict__ x, const float* __restrict__ x_pan,
    const float* __restrict__ theta_w, const float* __restrict__ theta_b,
    const float* __restrict__ phi_w,   const float* __restrict__ phi_b,
    const float* __restrict__ phi_pan_w, const float* __restrict__ phi_pan_b,
    float* __restrict__ T, float* __restrict__ Kp)
{
    const int p  = blockIdx.x;   // 0..23 (output row pair 2p, 2p+1)
    const int b  = blockIdx.y;   // 0..3
    const int cz = blockIdx.z;   // 0..2

    const float* xin  = (cz == 2) ? x_pan : x;
    const float* wgt  = (cz == 0) ? theta_w : (cz == 1 ? phi_w : phi_pan_w);
    const float* bias = (cz == 0) ? theta_b : (cz == 1 ? phi_b : phi_pan_b);

    // xs: 16 ci x 5 input rows x cols [-8..103] (zero padded), 16B-aligned rows
    __shared__ __align__(16) float xs[16][5][112];
    __shared__ float wsm[16][9][32];   // [ci][kh*3+kw][co]

    const int tid = threadIdx.x;
    const int co  = tid & 31;
    const int g   = tid >> 5;          // 0..7; ow in [6g, 6g+6)

    float acc[2][6];
    #pragma unroll
    for (int o = 0; o < 2; ++o)
        #pragma unroll
        for (int j = 0; j < 6; ++j) acc[o][j] = 0.f;

    const int row0 = 4*p - 1;

    for (int ci0 = 0; ci0 < CIN; ci0 += 16) {
        __syncthreads();
        // stage input rows (zero-pad out-of-range)
        for (int idx = tid; idx < 16*5*112; idx += 256) {
            int ci  = idx / (5*112);
            int rem = idx % (5*112);
            int rr  = rem / 112, cc = rem % 112;
            int row = row0 + rr, col = cc - 8;
            float v = 0.f;
            if (row >= 0 && row < HS && col >= 0 && col < WS)
                v = xin[((b*CIN + ci0 + ci)*HS + row)*WS + col];
            xs[ci][rr][cc] = v;
        }
        // stage weights transposed: w[co][ci][kh][kw] -> wsm[ci][kk][co]
        for (int idx = tid; idx < 16*9*32; idx += 256) {
            int c2 = idx & 31;
            int kk = (idx >> 5) % 9;
            int ci = idx / (9*32);
            wsm[ci][kk][c2] = wgt[(c2*CIN + ci0 + ci)*9 + kk];
        }
        __syncthreads();

        for (int ci = 0; ci < 16; ++ci) {
            float w9[9];
            #pragma unroll
            for (int kk = 0; kk < 9; ++kk) w9[kk] = wsm[ci][kk][co];

            #pragma unroll
            for (int rr = 0; rr < 5; ++rr) {
                // 16 cols starting at stored index 12g+4 (cols 12g-4 .. 12g+11)
                const float4* xr = (const float4*)&xs[ci][rr][12*g + 4];
                float4 t0 = xr[0], t1 = xr[1], t2 = xr[2], t3 = xr[3];
                float xv[16] = {t0.x,t0.y,t0.z,t0.w, t1.x,t1.y,t1.z,t1.w,
                                t2.x,t2.y,t2.z,t2.w, t3.x,t3.y,t3.z,t3.w};
                if (rr <= 2) {   // out row 2p, kh = rr
                    const int kh = rr;
                    #pragma unroll
                    for (int j = 0; j < 6; ++j)
                        #pragma unroll
                        for (int kw = 0; kw < 3; ++kw)
                            acc[0][j] += w9[kh*3+kw] * xv[3 + 2*j + kw];
                }
                if (rr >= 2) {   // out row 2p+1, kh = rr-2
                    const int kh = rr - 2;
                    #pragma unroll
                    for (int j = 0; j < 6; ++j)
                        #pragma unroll
                        for (int kw = 0; kw < 3; ++kw)
                            acc[1][j] += w9[kh*3+kw] * xv[3 + 2*j + kw];
                }
            }
        }
    }

    const float bv = bias[co];
    if (cz == 0) {
        #pragma unroll
        for (int o = 0; o < 2; ++o)
            #pragma unroll
            for (int j = 0; j < 6; ++j)
                T[((b*CMID + co)*H2 + (2*p + o))*W2 + (6*g + j)] = acc[o][j] + bv;
    } else {
        // maxpool2 over the 2x48 conv rows -> pooled row p, cols 3g..3g+2
        #pragma unroll
        for (int j3 = 0; j3 < 3; ++j3) {
            float m = fmaxf(fmaxf(acc[0][2*j3], acc[0][2*j3+1]),
                            fmaxf(acc[1][2*j3], acc[1][2*j3+1]));
            Kp[((((cz-1)*BB + b)*CMID + co)*H4 + p)*W4 + (3*g + j3)] = m + bv;
        }
    }
}

// ---------------------------------------------------------------------------
// K2: V = avgpool2(maxpool2(conv1x1(x))) for both branches.
// Block: (r4 0..23, bb 0..7). 256 threads: c = tid&31, sg = tid>>5,
// thread computes 3 pooled cols (s4 = 3sg..3sg+2), 16 conv accumulators each.
// ---------------------------------------------------------------------------
__global__ __launch_bounds__(256) void gconv_kernel(
    const float* __restrict__ x, const float* __restrict__ x_pan,
    const float* __restrict__ g_w, const float* __restrict__ g_b,
    const float* __restrict__ g_pan_w, const float* __restrict__ g_pan_b,
    float* __restrict__ Vv)
{
    const int r4 = blockIdx.x;      // 0..23
    const int bb = blockIdx.y;      // 0..7 = br*4 + b
    const int br = bb >> 2, b = bb & 3;
    const float* xin = br ? x_pan : x;
    const float* wg  = br ? g_pan_w : g_w;
    const float* bg  = br ? g_pan_b : g_b;

    __shared__ float wl[CIN][CMID];  // [ci][c]
    const int tid = threadIdx.x;
    for (int idx = tid; idx < CIN*CMID; idx += 256) {
        int c = idx >> 6, ci = idx & 63;   // source wg[c*64+ci], coalesced
        wl[ci][c] = wg[idx];
    }
    __syncthreads();

    const int c  = tid & 31;
    const int sg = tid >> 5;        // 0..7, pooled cols 3sg..3sg+2

    float acc[3][4][4];             // [s local][input row r][col dc]
    #pragma unroll
    for (int s = 0; s < 3; ++s)
        #pragma unroll
        for (int r = 0; r < 4; ++r)
            #pragma unroll
            for (int d = 0; d < 4; ++d) acc[s][r][d] = 0.f;

    for (int ci = 0; ci < CIN; ++ci) {
        const float wv = wl[ci][c];
        const float* xbase = &xin[((b*CIN + ci)*HS + 4*r4)*WS + 12*sg];
        #pragma unroll
        for (int r = 0; r < 4; ++r) {
            const float4* xp = (const float4*)(xbase + r*WS);
            #pragma unroll
            for (int s = 0; s < 3; ++s) {
                float4 xv = xp[s];
                acc[s][r][0] += wv*xv.x; acc[s][r][1] += wv*xv.y;
                acc[s][r][2] += wv*xv.z; acc[s][r][3] += wv*xv.w;
            }
        }
    }

    const float bv = bg[c];
    #pragma unroll
    for (int s = 0; s < 3; ++s) {
        float m00 = fmaxf(fmaxf(acc[s][0][0], acc[s][0][1]), fmaxf(acc[s][1][0], acc[s][1][1]));
        float m01 = fmaxf(fmaxf(acc[s][0][2], acc[s][0][3]), fmaxf(acc[s][1][2], acc[s][1][3]));
        float m10 = fmaxf(fmaxf(acc[s][2][0], acc[s][2][1]), fmaxf(acc[s][3][0], acc[s][3][1]));
        float m11 = fmaxf(fmaxf(acc[s][2][2], acc[s][2][3]), fmaxf(acc[s][3][2], acc[s][3][3]));
        Vv[((bb*CMID + c)*H4 + r4)*W4 + (3*sg + s)] = 0.25f*(m00+m01+m10+m11) + bv;
    }
}

// ---------------------------------------------------------------------------
// K3: attention over distinct grid. Q = T (b only), K = Kp[bb], V = Vv[bb].
// Block: (qt 0..143, bb 0..7): 16 queries x 576 keys. 256 threads:
// ql = tid&15 (query), ks = tid>>4 (key slice of 36). Two-pass softmax with
// scores in LDS; cross-slice reduction through reused LDS.
// ---------------------------------------------------------------------------
__global__ __launch_bounds__(256) void attn_kernel(
    const float* __restrict__ T, const float* __restrict__ Kp,
    const float* __restrict__ Vv, float* __restrict__ Y)
{
    const int qt = blockIdx.x;      // 0..143
    const int bb = blockIdx.y;      // 0..7
    const int b  = bb & 3;

    __shared__ float smem[256*37];  // scores ss[tid][0..35] stride 37; reused for partials
    __shared__ float pmax[16][16];  // [ks][ql]

    const int tid = threadIdx.x;
    const int ql  = tid & 15;
    const int ks  = tid >> 4;       // 0..15
    const int q   = qt*16 + ql;

    // load query vector (coalesced over ql lanes)
    float qv[32];
    const float* Tb = T + b*CMID*N2;
    #pragma unroll
    for (int c = 0; c < 32; ++c) qv[c] = Tb[c*N2 + q];

    const float* Kb = Kp + bb*CMID*M4;
    const float* Vb = Vv + bb*CMID*M4;
    float* myss = &smem[tid*37];

    // pass 1: scores + per-slice max
    float m = -1e30f;
    for (int j = 0; j < 36; j += 4) {
        const int k = ks*36 + j;
        float s0 = 0.f, s1 = 0.f, s2 = 0.f, s3 = 0.f;
        #pragma unroll
        for (int c = 0; c < 32; ++c) {
            float4 kv = *(const float4*)&Kb[c*M4 + k];
            s0 += qv[c]*kv.x; s1 += qv[c]*kv.y; s2 += qv[c]*kv.z; s3 += qv[c]*kv.w;
        }
        myss[j] = s0; myss[j+1] = s1; myss[j+2] = s2; myss[j+3] = s3;
        m = fmaxf(m, fmaxf(fmaxf(s0, s1), fmaxf(s2, s3)));
    }
    pmax[ks][ql] = m;
    __syncthreads();
    float M = pmax[0][ql];
    #pragma unroll
    for (int i = 1; i < 16; ++i) M = fmaxf(M, pmax[i][ql]);

    // pass 2: exp + AV partials
    float zp = 0.f;
    float av[32];
    #pragma unroll
    for (int c = 0; c < 32; ++c) av[c] = 0.f;
    for (int j = 0; j < 36; j += 4) {
        const int k = ks*36 + j;
        float p0 = __expf(myss[j]   - M);
        float p1 = __expf(myss[j+1] - M);
        float p2 = __expf(myss[j+2] - M);
        float p3 = __expf(myss[j+3] - M);
        zp += (p0 + p1) + (p2 + p3);
        #pragma unroll
        for (int c = 0; c < 32; ++c) {
            float4 vv = *(const float4*)&Vb[c*M4 + k];
            av[c] += p0*vv.x + p1*vv.y + p2*vv.z + p3*vv.w;
        }
    }
    __syncthreads();   // everyone done reading own scores; reuse smem

    // stash partials: accs[tid*33 + c], Z at smem[8448 + tid]
    #pragma unroll
    for (int c = 0; c < 32; ++c) smem[tid*33 + c] = av[c];
    smem[256*33 + tid] = zp;
    __syncthreads();

    // final reduce: thread (ql, ks) handles channels c = 2ks, 2ks+1
    float Z = 0.f;
    #pragma unroll
    for (int i = 0; i < 16; ++i) Z += smem[256*33 + i*16 + ql];
    const float inv = 1.0f / Z;
    float* Yb = Y + bb*CMID*N2;
    #pragma unroll
    for (int cc = 0; cc < 2; ++cc) {
        const int c = ks*2 + cc;
        float sum = 0.f;
        #pragma unroll
        for (int i = 0; i < 16; ++i) sum += smem[(i*16 + ql)*33 + c];
        Yb[c*N2 + q] = sum * inv;
    }
}

// ---------------------------------------------------------------------------
// K4: 1x1 W conv + BatchNorm(train, exact two-pass) + 2x2 nearest upsample.
// One block per output channel og (0..127): br = og>>6, o = og&63.
// Each thread: 9 float4 groups over the 4*2304 distinct (b,n) values.
// ---------------------------------------------------------------------------
__global__ __launch_bounds__(256) void wbn_kernel(
    const float* __restrict__ Y,
    const float* __restrict__ W_w, const float* __restrict__ W_b,
    const float* __restrict__ W_gamma, const float* __restrict__ W_beta,
    const float* __restrict__ Wp_w, const float* __restrict__ Wp_b,
    const float* __restrict__ Wp_gamma, const float* __restrict__ Wp_beta,
    float* __restrict__ out)
{
    const int og = blockIdx.x;      // 0..127 = output channel in concat
    const int br = og >> 6, o = og & 63;
    const float* Ww = br ? Wp_w : W_w;
    const float  bias = (br ? Wp_b : W_b)[o];
    const float* Ybase = Y + br*BB*CMID*N2;

    float wreg[32];
    #pragma unroll
    for (int c = 0; c < 32; ++c) wreg[c] = Ww[o*CMID + c];

    __shared__ float rbuf[256];
    const int tid = threadIdx.x;

    float4 zloc[9];
    float psum = 0.f;
    #pragma unroll
    for (int i = 0; i < 9; ++i) {
        const int g4 = tid + 256*i;            // 0..2303 (group of 4 values)
        const int b  = g4 / 576;
        const int n4 = (g4 % 576) * 4;
        const float* yb = Ybase + b*CMID*N2 + n4;
        float4 a = {0.f, 0.f, 0.f, 0.f};
        #pragma unroll
        for (int c = 0; c < 32; ++c) {
            float4 yv = *(const float4*)&yb[c*N2];
            a.x += wreg[c]*yv.x; a.y += wreg[c]*yv.y;
            a.z += wreg[c]*yv.z; a.w += wreg[c]*yv.w;
        }
        a.x += bias; a.y += bias; a.z += bias; a.w += bias;
        zloc[i] = a;
        psum += (a.x + a.y) + (a.z + a.w);
    }

    // mean
    rbuf[tid] = psum;
    __syncthreads();
    for (int sft = 128; sft > 0; sft >>= 1) {
        if (tid < sft) rbuf[tid] += rbuf[tid + sft];
        __syncthreads();
    }
    const float mean = rbuf[0] * (1.0f/9216.0f);
    __syncthreads();

    // variance (two-pass, biased -- matches jnp.var)
    float pvar = 0.f;
    #pragma unroll
    for (int i = 0; i < 9; ++i) {
        float4 a = zloc[i];
        float d0 = a.x - mean, d1 = a.y - mean, d2 = a.z - mean, d3 = a.w - mean;
        pvar += (d0*d0 + d1*d1) + (d2*d2 + d3*d3);
    }
    rbuf[tid] = pvar;
    __syncthreads();
    for (int sft = 128; sft > 0; sft >>= 1) {
        if (tid < sft) rbuf[tid] += rbuf[tid + sft];
        __syncthreads();
    }
    const float var = rbuf[0] * (1.0f/9216.0f);

    const float gamma = (br ? Wp_gamma : W_gamma)[o];
    const float beta  = (br ? Wp_beta  : W_beta)[o];
    const float scale = gamma * rsqrtf(var + 1e-5f);
    const float shift = beta - mean*scale;

    // upsampled write: each distinct value fills a 2x2 block
    #pragma unroll
    for (int i = 0; i < 9; ++i) {
        const int g4 = tid + 256*i;
        const int b  = g4 / 576;
        const int nn = (g4 % 576) * 4;
        const int r  = nn / W2, s = nn % W2;
        float4 a = zloc[i];
        float v0 = a.x*scale + shift, v1 = a.y*scale + shift;
        float v2 = a.z*scale + shift, v3 = a.w*scale + shift;
        float4 lo = {v0, v0, v1, v1};
        float4 hi = {v2, v2, v3, v3};
        float* ob = out + ((size_t)(b*128 + og)*HS + 2*r)*WS + 2*s;
        *(float4*)(ob)        = lo;
        *(float4*)(ob + 4)    = hi;
        *(float4*)(ob + WS)   = lo;
        *(float4*)(ob + WS+4) = hi;
    }
}

// ---------------------------------------------------------------------------
extern "C" void kernel_launch(void* const* d_in, const int* in_sizes, int n_in,
                              void* d_out, int out_size, void* d_ws, size_t ws_size,
                              hipStream_t stream) {
    (void)in_sizes; (void)n_in; (void)out_size; (void)ws_size;
    const float* x         = (const float*)d_in[0];
    const float* x_pan     = (const float*)d_in[1];
    const float* g_w       = (const float*)d_in[2];
    const float* g_b       = (const float*)d_in[3];
    const float* g_pan_w   = (const float*)d_in[4];
    const float* g_pan_b   = (const float*)d_in[5];
    const float* theta_w   = (const float*)d_in[6];
    const float* theta_b   = (const float*)d_in[7];
    const float* phi_w     = (const float*)d_in[8];
    const float* phi_b     = (const float*)d_in[9];
    const float* phi_pan_w = (const float*)d_in[10];
    const float* phi_pan_b = (const float*)d_in[11];
    const float* W_w       = (const float*)d_in[12];
    const float* W_b       = (const float*)d_in[13];
    const float* W_gamma   = (const float*)d_in[14];
    const float* W_beta    = (const float*)d_in[15];
    const float* Wp_w      = (const float*)d_in[16];
    const float* Wp_b      = (const float*)d_in[17];
    const float* Wp_gamma  = (const float*)d_in[18];
    const float* Wp_beta   = (const float*)d_in[19];

    float* out = (float*)d_out;
    float* ws  = (float*)d_ws;

    // workspace layout (floats)
    float* T  = ws;                       // [4][32][48][48]   = 294912
    float* Kp = T  + BB*CMID*N2;          // [2][4][32][24][24]= 147456
    float* Vv = Kp + 2*BB*CMID*M4;        // [2][4][32][24][24]= 147456
    float* Yw = Vv + 2*BB*CMID*M4;        // [2][4][32][48][48]= 589824

    conv3x3_kernel<<<dim3(24, BB, 3), 256, 0, stream>>>(
        x, x_pan, theta_w, theta_b, phi_w, phi_b, phi_pan_w, phi_pan_b, T, Kp);
    gconv_kernel<<<dim3(24, 8), 256, 0, stream>>>(
        x, x_pan, g_w, g_b, g_pan_w, g_pan_b, Vv);
    attn_kernel<<<dim3(144, 8), 256, 0, stream>>>(T, Kp, Vv, Yw);
    wbn_kernel<<<dim3(128), 256, 0, stream>>>(
        Yw, W_w, W_b, W_gamma, W_beta, Wp_w, Wp_b, Wp_gamma, Wp_beta, out);
}